// Round 5
// baseline (436.395 us; speedup 1.0000x reference)
//
#include <hip/hip_runtime.h>

#define TOK   16384
#define DIM   1024
#define INNER 4096
#define EPSF  1e-5f

typedef int v4i  __attribute__((ext_vector_type(4)));
typedef int v16i __attribute__((ext_vector_type(16)));

static __device__ __forceinline__ void async_copy16(const char* g, char* l) {
    __builtin_amdgcn_global_load_lds(
        (const __attribute__((address_space(1))) unsigned int*)g,
        (__attribute__((address_space(3))) unsigned int*)l, 16, 0, 0);
}

static __device__ __forceinline__ float bf2f(unsigned short u) {
    return __uint_as_float(((unsigned)u) << 16);
}
static __device__ __forceinline__ unsigned short f2bf(float f) {
    unsigned u = __float_as_uint(f);
    return (unsigned short)((u + 0x7fffu + ((u >> 16) & 1u)) >> 16);  // RNE
}

// erf via Abramowitz-Stegun 7.1.26, |abs err| <= 1.5e-7
static __device__ __forceinline__ float fast_erf(float z) {
    float az = fabsf(z);
    float tt = __builtin_amdgcn_rcpf(1.f + 0.3275911f * az);
    float poly = ((((1.061405429f * tt - 1.453152027f) * tt + 1.421413741f) * tt
                   - 0.284496736f) * tt + 0.254829592f) * tt;
    float er = 1.f - poly * __expf(-az * az);
    return copysignf(er, z);
}
static __device__ __forceinline__ float gelu_exact(float v) {
    return 0.5f * v * (1.f + fast_erf(v * 0.70710678118654752f));
}

static __device__ __forceinline__ float waveSum(float v) {
#pragma unroll
    for (int o = 32; o > 0; o >>= 1) v += __shfl_down(v, o, 64);
    return v;
}
static __device__ __forceinline__ float waveMax(float v) {
#pragma unroll
    for (int o = 32; o > 0; o >>= 1) v = fmaxf(v, __shfl_down(v, o, 64));
    return v;
}

// ---- per-tensor sum(|w|) reduction (f32 in) ----
__global__ void absmean_k(const float* __restrict__ w, int n4, float* __restrict__ acc) {
    int idx = blockIdx.x * blockDim.x + threadIdx.x;
    int stride = gridDim.x * blockDim.x;
    const float4* w4 = (const float4*)w;
    float s = 0.f;
    for (int i = idx; i < n4; i += stride) {
        float4 v = w4[i];
        s += fabsf(v.x) + fabsf(v.y) + fabsf(v.z) + fabsf(v.w);
    }
    __shared__ float sp[4];
    int wv = threadIdx.x >> 6, lane = threadIdx.x & 63;
    s = waveSum(s);
    if (lane == 0) sp[wv] = s;
    __syncthreads();
    if (threadIdx.x == 0) atomicAdd(acc, sp[0] + sp[1] + sp[2] + sp[3]);
}

// ---- per-tensor ternary quantize: wq = clip(round(w/clip(mean|w|,eps)),-1,1) ----
__global__ void wquant_k(const float* __restrict__ w, int n,
                         const float* __restrict__ acc, float* __restrict__ wscale,
                         char* __restrict__ wq) {
    float mean = *acc / (float)n;
    float cl = fmaxf(mean, EPSF);
    float s = 1.f / cl;
    if (blockIdx.x == 0 && threadIdx.x == 0) *wscale = cl;  // dequant factor
    int idx = blockIdx.x * blockDim.x + threadIdx.x;
    int stride = gridDim.x * blockDim.x;
    int n4 = n >> 2;
    const float4* w4 = (const float4*)w;
    unsigned* q4 = (unsigned*)wq;
    for (int i = idx; i < n4; i += stride) {
        float4 v = w4[i];
        float e[4] = {v.x, v.y, v.z, v.w};
        unsigned packed = 0;
#pragma unroll
        for (int j = 0; j < 4; j++) {
            float r = rintf(e[j] * s);
            r = fminf(fmaxf(r, -1.f), 1.f);
            packed |= ((unsigned)((int)r & 0xff)) << (8 * j);
        }
        q4[i] = packed;
    }
}

// ---- RMSNorm + per-token absmax int8 quant, f32 input. One block per row. ----
template <int D, int VPT>
__global__ void actquant_f32_k(const float* __restrict__ X, char* __restrict__ Q,
                               float* __restrict__ rs_out) {
    int token = blockIdx.x;
    int t = threadIdx.x;
    const float4* xp = (const float4*)(X + (long)token * D);
    float vals[VPT];
    float ss = 0.f, am = 0.f;
#pragma unroll
    for (int j = 0; j < VPT / 4; j++) {
        float4 v = xp[t * (VPT / 4) + j];
        vals[4 * j] = v.x; vals[4 * j + 1] = v.y; vals[4 * j + 2] = v.z; vals[4 * j + 3] = v.w;
        ss += v.x * v.x + v.y * v.y + v.z * v.z + v.w * v.w;
        am = fmaxf(am, fmaxf(fmaxf(fabsf(v.x), fabsf(v.y)), fmaxf(fabsf(v.z), fabsf(v.w))));
    }
    __shared__ float sp[8];
    __shared__ float bc[2];
    int wv = t >> 6, lane = t & 63;
    float S = waveSum(ss);
    float M = waveMax(am);
    if (lane == 0) { sp[wv] = S; sp[4 + wv] = M; }
    __syncthreads();
    if (t == 0) {
        float Sa = sp[0] + sp[1] + sp[2] + sp[3];
        float Ma = fmaxf(fmaxf(sp[4], sp[5]), fmaxf(sp[6], sp[7]));
        float rinv = rsqrtf(Sa * (1.f / (float)D) + EPSF);   // rsqrt(mean(x^2)+eps)
        float amn = Ma * rinv;                                // absmax of normalized row
        float scale = 127.f / fmaxf(amn, EPSF);
        rs_out[token] = 1.f / scale;                          // dequant factor
        bc[0] = rinv; bc[1] = scale;
    }
    __syncthreads();
    float rinv = bc[0], scale = bc[1];
    unsigned outw[VPT / 4];
#pragma unroll
    for (int j = 0; j < VPT; j++) {
        float r = rintf((vals[j] * rinv) * scale);
        r = fminf(fmaxf(r, -128.f), 127.f);
        unsigned qi = (unsigned)((int)r & 0xff) << (8 * (j & 3));
        if ((j & 3) == 0) outw[j / 4] = qi; else outw[j / 4] |= qi;
    }
    unsigned* qp = (unsigned*)(Q + (long)token * D);
#pragma unroll
    for (int j = 0; j < VPT / 4; j++) qp[t * (VPT / 4) + j] = outw[j];
}

// ---- GELU + RMSNorm + int8 quant, bf16 input (pre-activation h). ----
template <int D, int VPT>  // VPT must be 16
__global__ void actquant_bf16_k(const unsigned short* __restrict__ X, char* __restrict__ Q,
                                float* __restrict__ rs_out) {
    int token = blockIdx.x;
    int t = threadIdx.x;
    const uint4* xp = (const uint4*)(X + (long)token * D);
    float vals[VPT];
    float ss = 0.f, am = 0.f;
#pragma unroll
    for (int j = 0; j < VPT / 8; j++) {
        uint4 v = xp[t * (VPT / 8) + j];
        unsigned ws[4] = {v.x, v.y, v.z, v.w};
#pragma unroll
        for (int p = 0; p < 4; p++) {
            float f0 = gelu_exact(bf2f((unsigned short)(ws[p] & 0xffff)));
            float f1 = gelu_exact(bf2f((unsigned short)(ws[p] >> 16)));
            vals[8 * j + 2 * p] = f0; vals[8 * j + 2 * p + 1] = f1;
            ss += f0 * f0 + f1 * f1;
            am = fmaxf(am, fmaxf(fabsf(f0), fabsf(f1)));
        }
    }
    __shared__ float sp[8];
    __shared__ float bc[2];
    int wv = t >> 6, lane = t & 63;
    float S = waveSum(ss);
    float M = waveMax(am);
    if (lane == 0) { sp[wv] = S; sp[4 + wv] = M; }
    __syncthreads();
    if (t == 0) {
        float Sa = sp[0] + sp[1] + sp[2] + sp[3];
        float Ma = fmaxf(fmaxf(sp[4], sp[5]), fmaxf(sp[6], sp[7]));
        float rinv = rsqrtf(Sa * (1.f / (float)D) + EPSF);
        float amn = Ma * rinv;
        float scale = 127.f / fmaxf(amn, EPSF);
        rs_out[token] = 1.f / scale;
        bc[0] = rinv; bc[1] = scale;
    }
    __syncthreads();
    float rinv = bc[0], scale = bc[1];
    unsigned outw[4];
#pragma unroll
    for (int j = 0; j < VPT; j++) {
        float r = rintf((vals[j] * rinv) * scale);
        r = fminf(fmaxf(r, -128.f), 127.f);
        unsigned qi = (unsigned)((int)r & 0xff) << (8 * (j & 3));
        if ((j & 3) == 0) outw[j / 4] = qi; else outw[j / 4] |= qi;
    }
    uint4* qp = (uint4*)(Q + (long)token * D);
    qp[t] = make_uint4(outw[0], outw[1], outw[2], outw[3]);
}

// ---- int8 GEMM: 256x128 tile, BK=64, 256 thr (4 waves 2Mx2N), wave tile 128x64 ----
// R3's kernel (stripe layout, 0 conflicts measured, coalesced staging, 2 blocks/CU)
// with ONE change: per-tile drain-0 double-buffer -> TRIPLE-buffered 2-tile-deep
// prefetch with counted vmcnt (T4). m218: 8ph-with-drain0 ~ 1ph; counted-vs-drain0
// = +38-73%. Here: during tile T we stage T+2; boundary wait is vmcnt(6) (T+2's
// 6 loads stay in flight, T+1 proven landed). Loads get >=1 full tile (~2000 cyc)
// of slack -> straggler HBM/L2 tails leave the critical path. vmcnt never drains
// to 0 until the last two tiles.
//
// STRIPE layout (unchanged from R3): stripe = 16 rows x 64 B; byte(row,slot) =
// (row>>4)*1024 + slot*256 + (row&15)*16 == lane*16 for the staging lane ->
// linear gload_lds dest, row-major coalesced source, fragment reads = 2x256B
// contiguous runs, 0 bank conflicts (measured R3/R4).
template <int OUT_F32>
__global__ __launch_bounds__(256, 2) void gemm4_k(
    const char* __restrict__ A, const char* __restrict__ Bw,
    const float* __restrict__ rs, const float* __restrict__ wscale_p,
    const float* __restrict__ bias, void* __restrict__ outp,
    int M, int N, int K) {
    __shared__ char L[73728];  // A: 3 x 16 KB at 0; B: 3 x 8 KB at 49152
    int t = threadIdx.x;
    int lane = t & 63, wv = t >> 6;
    int l31 = lane & 31, kh = lane >> 5;
    int wmi = wv >> 1, wni = wv & 1;  // wave tile rows wmi*128+[0,128), cols wni*64+[0,64)

    // XCD-chunked swizzle (grid sizes are multiples of 8)
    int gx = gridDim.x;
    int nwg = gx * gridDim.y;
    int bid = blockIdx.y * gx + blockIdx.x;
    int swz = (bid & 7) * (nwg >> 3) + (bid >> 3);
    int bx = swz % gx, by = swz / gx;
    int m0 = by * 256, n0 = bx * 128;

    // staging: call q covers stripes q*4+wv (rows q*64 + wv*16 + (lane&15)),
    // lane's 16B chunk at global col (lane>>4)*16; LDS dest linear lane*16.
    const char* srcA = A  + (long)(m0 + wv * 16 + (lane & 15)) * K + ((lane >> 4) * 16);
    const char* srcB = Bw + (long)(n0 + wv * 16 + (lane & 15)) * K + ((lane >> 4) * 16);
    char* dstA = L + wv * 1024 + lane * 16;
    char* dstB = L + 49152 + wv * 1024 + lane * 16;

    auto stA = [&](int Tt, int q, int bo) {  // q in 0..3, bo in {0,16384,32768}
        async_copy16(srcA + (long)q * 64 * K + ((long)Tt << 6),
                     dstA + bo + q * 4096);
    };
    auto stB = [&](int Tt, int q, int bo) {  // q in 0..1, B offset = bo/2
        async_copy16(srcB + (long)q * 64 * K + ((long)Tt << 6),
                     dstB + (bo >> 1) + q * 4096);
    };

    // fragment read offsets: off(row) = (row>>4)*1024 + (row&15)*16, + slot*256
    int offA[4], offB[2];
#pragma unroll
    for (int i = 0; i < 4; i++) {
        int r = wmi * 128 + i * 32 + l31;
        offA[i] = (r >> 4) * 1024 + (r & 15) * 16 + kh * 256;
    }
#pragma unroll
    for (int j = 0; j < 2; j++) {
        int r = wni * 64 + j * 32 + l31;
        offB[j] = (r >> 4) * 1024 + (r & 15) * 16 + kh * 256;
    }

    v16i acc[4][2] = {};
    int nK = K >> 6;

    // triple-buffer rotation: read r0, next tile in r1, stage T+2 into r2
    int r0 = 0, r1 = 16384, r2 = 32768;

    // prologue: stage T0 into r0 and T1 into r1 (12 loads); T0 landed when <=6 left
    stA(0, 0, 0); stA(0, 1, 0); stA(0, 2, 0); stA(0, 3, 0); stB(0, 0, 0); stB(0, 1, 0);
    stA(1, 0, 16384); stA(1, 1, 16384); stA(1, 2, 16384); stA(1, 3, 16384);
    stB(1, 0, 16384); stB(1, 1, 16384);
    asm volatile("s_waitcnt vmcnt(6)" ::: "memory");
    asm volatile("s_barrier" ::: "memory");

    for (int T = 0; T < nK; ++T) {
        const char* pA = L + r0;
        const char* pB = L + 49152 + (r0 >> 1);
        bool pre = (T + 2 < nK);
#pragma unroll
        for (int ks = 0; ks < 2; ++ks) {
            v4i a0 = *(const v4i*)(pA + offA[0] + ks * 512);
            v4i a1 = *(const v4i*)(pA + offA[1] + ks * 512);
            v4i a2 = *(const v4i*)(pA + offA[2] + ks * 512);
            v4i a3 = *(const v4i*)(pA + offA[3] + ks * 512);
            v4i b0 = *(const v4i*)(pB + offB[0] + ks * 512);
            v4i b1 = *(const v4i*)(pB + offB[1] + ks * 512);
            if (pre) {
                if (ks == 0) { stA(T + 2, 0, r2); stA(T + 2, 1, r2); stB(T + 2, 0, r2); }
                else         { stA(T + 2, 2, r2); stA(T + 2, 3, r2); stB(T + 2, 1, r2); }
            }
            __builtin_amdgcn_s_setprio(1);
            acc[0][0] = __builtin_amdgcn_mfma_i32_32x32x32_i8(a0, b0, acc[0][0], 0, 0, 0);
            acc[0][1] = __builtin_amdgcn_mfma_i32_32x32x32_i8(a0, b1, acc[0][1], 0, 0, 0);
            acc[1][0] = __builtin_amdgcn_mfma_i32_32x32x32_i8(a1, b0, acc[1][0], 0, 0, 0);
            acc[1][1] = __builtin_amdgcn_mfma_i32_32x32x32_i8(a1, b1, acc[1][1], 0, 0, 0);
            acc[2][0] = __builtin_amdgcn_mfma_i32_32x32x32_i8(a2, b0, acc[2][0], 0, 0, 0);
            acc[2][1] = __builtin_amdgcn_mfma_i32_32x32x32_i8(a2, b1, acc[2][1], 0, 0, 0);
            acc[3][0] = __builtin_amdgcn_mfma_i32_32x32x32_i8(a3, b0, acc[3][0], 0, 0, 0);
            acc[3][1] = __builtin_amdgcn_mfma_i32_32x32x32_i8(a3, b1, acc[3][1], 0, 0, 0);
            __builtin_amdgcn_s_setprio(0);
        }
        // boundary: T+1 proven landed (<=6 outstanding = T+2's own loads); never 0
        // until the tail (pre==false: nothing new issued, drain T+1 exactly).
        if (pre) asm volatile("s_waitcnt vmcnt(6)" ::: "memory");
        else     asm volatile("s_waitcnt vmcnt(0)" ::: "memory");
        asm volatile("s_barrier" ::: "memory");
        int tt = r0; r0 = r1; r1 = r2; r2 = tt;
    }

    // Epilogue. 32x32 C/D layout: col = lane&31, row = (reg&3) + 8*(reg>>2) + 4*(lane>>5)
    float wsc = *wscale_p;
    float bv[2];
#pragma unroll
    for (int j = 0; j < 2; j++) bv[j] = bias[n0 + wni * 64 + j * 32 + l31];
#pragma unroll
    for (int i = 0; i < 4; i++) {
        int mbase = m0 + wmi * 128 + i * 32 + 4 * kh;
        float fsv[16];
#pragma unroll
        for (int rg = 0; rg < 16; rg++)
            fsv[rg] = rs[mbase + (rg & 3) + 8 * (rg >> 2)] * wsc;
#pragma unroll
        for (int j = 0; j < 2; j++) {
            int ng = n0 + wni * 64 + j * 32 + l31;
#pragma unroll
            for (int rg = 0; rg < 16; rg++) {
                int mg = mbase + (rg & 3) + 8 * (rg >> 2);
                float v = (float)acc[i][j][rg] * fsv[rg] + bv[j];
                long idx = (long)mg * N + ng;
                if (OUT_F32) ((float*)outp)[idx] = v;
                else ((unsigned short*)outp)[idx] = f2bf(v);
            }
        }
    }
}

extern "C" void kernel_launch(void* const* d_in, const int* in_sizes, int n_in,
                              void* d_out, int out_size, void* d_ws, size_t ws_size,
                              hipStream_t stream) {
    const float* x  = (const float*)d_in[0];
    const float* w1 = (const float*)d_in[1];
    const float* b1 = (const float*)d_in[2];
    const float* w2 = (const float*)d_in[3];
    const float* b2 = (const float*)d_in[4];
    float* out = (float*)d_out;

    char* ws = (char*)d_ws;
    float* acc1 = (float*)(ws + 0);
    float* acc2 = (float*)(ws + 4);
    float* wsc1 = (float*)(ws + 8);
    float* wsc2 = (float*)(ws + 12);
    size_t off = 256;
    char* w1q = ws + off; off += (size_t)INNER * DIM;        // 4 MB
    char* w2q = ws + off; off += (size_t)INNER * DIM;        // 4 MB
    char* xq1 = ws + off; off += (size_t)TOK * DIM;          // 16 MB
    float* rs1 = (float*)(ws + off); off += (size_t)TOK * 4; // 64 KB
    char* xq2 = ws + off; off += (size_t)TOK * INNER;        // 64 MB
    float* rs2 = (float*)(ws + off); off += (size_t)TOK * 4; // 64 KB
    unsigned short* h = (unsigned short*)(ws + off);         // 128 MB bf16 (pre-GELU)

    hipMemsetAsync(d_ws, 0, 16, stream);

    int nw = INNER * DIM;
    absmean_k<<<1024, 256, 0, stream>>>(w1, nw / 4, acc1);
    absmean_k<<<1024, 256, 0, stream>>>(w2, nw / 4, acc2);
    wquant_k<<<2048, 256, 0, stream>>>(w1, nw, acc1, wsc1, w1q);
    wquant_k<<<2048, 256, 0, stream>>>(w2, nw, acc2, wsc2, w2q);

    actquant_f32_k<DIM, 4><<<TOK, 256, 0, stream>>>(x, xq1, rs1);
    gemm4_k<0><<<dim3(INNER / 128, TOK / 256), 256, 0, stream>>>(
        xq1, w1q, rs1, wsc1, b1, (void*)h, TOK, INNER, DIM);
    actquant_bf16_k<INNER, 16><<<TOK, 256, 0, stream>>>(h, xq2, rs2);
    gemm4_k<1><<<dim3(DIM / 128, TOK / 256), 256, 0, stream>>>(
        xq2, w2q, rs2, wsc2, b2, (void*)out, TOK, DIM, INNER);
}

// Round 6
// 390.350 us; speedup vs baseline: 1.1180x; 1.1180x over previous
//
#include <hip/hip_runtime.h>

#define TOK   16384
#define DIM   1024
#define INNER 4096
#define EPSF  1e-5f

typedef int v4i  __attribute__((ext_vector_type(4)));
typedef int v16i __attribute__((ext_vector_type(16)));

static __device__ __forceinline__ void async_copy16(const char* g, char* l) {
    __builtin_amdgcn_global_load_lds(
        (const __attribute__((address_space(1))) unsigned int*)g,
        (__attribute__((address_space(3))) unsigned int*)l, 16, 0, 0);
}

static __device__ __forceinline__ float bf2f(unsigned short u) {
    return __uint_as_float(((unsigned)u) << 16);
}
static __device__ __forceinline__ unsigned short f2bf(float f) {
    unsigned u = __float_as_uint(f);
    return (unsigned short)((u + 0x7fffu + ((u >> 16) & 1u)) >> 16);  // RNE
}

// erf via Abramowitz-Stegun 7.1.26, |abs err| <= 1.5e-7
static __device__ __forceinline__ float fast_erf(float z) {
    float az = fabsf(z);
    float tt = __builtin_amdgcn_rcpf(1.f + 0.3275911f * az);
    float poly = ((((1.061405429f * tt - 1.453152027f) * tt + 1.421413741f) * tt
                   - 0.284496736f) * tt + 0.254829592f) * tt;
    float er = 1.f - poly * __expf(-az * az);
    return copysignf(er, z);
}
static __device__ __forceinline__ float gelu_exact(float v) {
    return 0.5f * v * (1.f + fast_erf(v * 0.70710678118654752f));
}

static __device__ __forceinline__ float waveSum(float v) {
#pragma unroll
    for (int o = 32; o > 0; o >>= 1) v += __shfl_down(v, o, 64);
    return v;
}
static __device__ __forceinline__ float waveMax(float v) {
#pragma unroll
    for (int o = 32; o > 0; o >>= 1) v = fmaxf(v, __shfl_down(v, o, 64));
    return v;
}

// ---- per-tensor sum(|w|) reduction (f32 in) ----
__global__ void absmean_k(const float* __restrict__ w, int n4, float* __restrict__ acc) {
    int idx = blockIdx.x * blockDim.x + threadIdx.x;
    int stride = gridDim.x * blockDim.x;
    const float4* w4 = (const float4*)w;
    float s = 0.f;
    for (int i = idx; i < n4; i += stride) {
        float4 v = w4[i];
        s += fabsf(v.x) + fabsf(v.y) + fabsf(v.z) + fabsf(v.w);
    }
    __shared__ float sp[4];
    int wv = threadIdx.x >> 6, lane = threadIdx.x & 63;
    s = waveSum(s);
    if (lane == 0) sp[wv] = s;
    __syncthreads();
    if (threadIdx.x == 0) atomicAdd(acc, sp[0] + sp[1] + sp[2] + sp[3]);
}

// ---- per-tensor ternary quantize: wq = clip(round(w/clip(mean|w|,eps)),-1,1) ----
__global__ void wquant_k(const float* __restrict__ w, int n,
                         const float* __restrict__ acc, float* __restrict__ wscale,
                         char* __restrict__ wq) {
    float mean = *acc / (float)n;
    float cl = fmaxf(mean, EPSF);
    float s = 1.f / cl;
    if (blockIdx.x == 0 && threadIdx.x == 0) *wscale = cl;  // dequant factor
    int idx = blockIdx.x * blockDim.x + threadIdx.x;
    int stride = gridDim.x * blockDim.x;
    int n4 = n >> 2;
    const float4* w4 = (const float4*)w;
    unsigned* q4 = (unsigned*)wq;
    for (int i = idx; i < n4; i += stride) {
        float4 v = w4[i];
        float e[4] = {v.x, v.y, v.z, v.w};
        unsigned packed = 0;
#pragma unroll
        for (int j = 0; j < 4; j++) {
            float r = rintf(e[j] * s);
            r = fminf(fmaxf(r, -1.f), 1.f);
            packed |= ((unsigned)((int)r & 0xff)) << (8 * j);
        }
        q4[i] = packed;
    }
}

// ---- RMSNorm + per-token absmax int8 quant, f32 input. One block per row. ----
template <int D, int VPT>
__global__ void actquant_f32_k(const float* __restrict__ X, char* __restrict__ Q,
                               float* __restrict__ rs_out) {
    int token = blockIdx.x;
    int t = threadIdx.x;
    const float4* xp = (const float4*)(X + (long)token * D);
    float vals[VPT];
    float ss = 0.f, am = 0.f;
#pragma unroll
    for (int j = 0; j < VPT / 4; j++) {
        float4 v = xp[t * (VPT / 4) + j];
        vals[4 * j] = v.x; vals[4 * j + 1] = v.y; vals[4 * j + 2] = v.z; vals[4 * j + 3] = v.w;
        ss += v.x * v.x + v.y * v.y + v.z * v.z + v.w * v.w;
        am = fmaxf(am, fmaxf(fmaxf(fabsf(v.x), fabsf(v.y)), fmaxf(fabsf(v.z), fabsf(v.w))));
    }
    __shared__ float sp[8];
    __shared__ float bc[2];
    int wv = t >> 6, lane = t & 63;
    float S = waveSum(ss);
    float M = waveMax(am);
    if (lane == 0) { sp[wv] = S; sp[4 + wv] = M; }
    __syncthreads();
    if (t == 0) {
        float Sa = sp[0] + sp[1] + sp[2] + sp[3];
        float Ma = fmaxf(fmaxf(sp[4], sp[5]), fmaxf(sp[6], sp[7]));
        float rinv = rsqrtf(Sa * (1.f / (float)D) + EPSF);   // rsqrt(mean(x^2)+eps)
        float amn = Ma * rinv;                                // absmax of normalized row
        float scale = 127.f / fmaxf(amn, EPSF);
        rs_out[token] = 1.f / scale;                          // dequant factor
        bc[0] = rinv; bc[1] = scale;
    }
    __syncthreads();
    float rinv = bc[0], scale = bc[1];
    unsigned outw[VPT / 4];
#pragma unroll
    for (int j = 0; j < VPT; j++) {
        float r = rintf((vals[j] * rinv) * scale);
        r = fminf(fmaxf(r, -128.f), 127.f);
        unsigned qi = (unsigned)((int)r & 0xff) << (8 * (j & 3));
        if ((j & 3) == 0) outw[j / 4] = qi; else outw[j / 4] |= qi;
    }
    unsigned* qp = (unsigned*)(Q + (long)token * D);
#pragma unroll
    for (int j = 0; j < VPT / 4; j++) qp[t * (VPT / 4) + j] = outw[j];
}

// ---- GELU + RMSNorm + int8 quant, bf16 input (pre-activation h). ----
template <int D, int VPT>  // VPT must be 16
__global__ void actquant_bf16_k(const unsigned short* __restrict__ X, char* __restrict__ Q,
                                float* __restrict__ rs_out) {
    int token = blockIdx.x;
    int t = threadIdx.x;
    const uint4* xp = (const uint4*)(X + (long)token * D);
    float vals[VPT];
    float ss = 0.f, am = 0.f;
#pragma unroll
    for (int j = 0; j < VPT / 8; j++) {
        uint4 v = xp[t * (VPT / 8) + j];
        unsigned ws[4] = {v.x, v.y, v.z, v.w};
#pragma unroll
        for (int p = 0; p < 4; p++) {
            float f0 = gelu_exact(bf2f((unsigned short)(ws[p] & 0xffff)));
            float f1 = gelu_exact(bf2f((unsigned short)(ws[p] >> 16)));
            vals[8 * j + 2 * p] = f0; vals[8 * j + 2 * p + 1] = f1;
            ss += f0 * f0 + f1 * f1;
            am = fmaxf(am, fmaxf(fabsf(f0), fabsf(f1)));
        }
    }
    __shared__ float sp[8];
    __shared__ float bc[2];
    int wv = t >> 6, lane = t & 63;
    float S = waveSum(ss);
    float M = waveMax(am);
    if (lane == 0) { sp[wv] = S; sp[4 + wv] = M; }
    __syncthreads();
    if (t == 0) {
        float Sa = sp[0] + sp[1] + sp[2] + sp[3];
        float Ma = fmaxf(fmaxf(sp[4], sp[5]), fmaxf(sp[6], sp[7]));
        float rinv = rsqrtf(Sa * (1.f / (float)D) + EPSF);
        float amn = Ma * rinv;
        float scale = 127.f / fmaxf(amn, EPSF);
        rs_out[token] = 1.f / scale;
        bc[0] = rinv; bc[1] = scale;
    }
    __syncthreads();
    float rinv = bc[0], scale = bc[1];
    unsigned outw[4];
#pragma unroll
    for (int j = 0; j < VPT; j++) {
        float r = rintf((vals[j] * rinv) * scale);
        r = fminf(fmaxf(r, -128.f), 127.f);
        unsigned qi = (unsigned)((int)r & 0xff) << (8 * (j & 3));
        if ((j & 3) == 0) outw[j / 4] = qi; else outw[j / 4] |= qi;
    }
    uint4* qp = (uint4*)(Q + (long)token * D);
    qp[t] = make_uint4(outw[0], outw[1], outw[2], outw[3]);
}

// ---- int8 GEMM: 256x256, BK=128, 512 thr (8 waves, INTERLEAVED 2Mx4N), m201 ring ----
// Fusion of the three proven ingredients:
//  * R1's ring (= m201): interleaved wave tiling (wave rows {ih*128+il*64+wmi*32},
//    cols {jh*128+wni*32}) makes each phase touch ONE A-half and ONE B-half, so
//    staging into the CURRENT buffer right after a half's last-read phase is
//    race-free (its ds_reads provably returned before that phase's MFMA lgkmcnt,
//    two barriers earlier). Stage order {T+1.A0 @p0, T+1.B1 @p1, T+2.B0 @p2,
//    T+2.A1 @p3}; boundary s_waitcnt vmcnt(4): every half has 4-7 phases of
//    landing slack and vmcnt NEVER drains below 4 until the tail (T4).
//  * R3's stripe LDS layout (measured 0 conflicts): per 16 KB half-region, 2
//    k-cols (64 B) x [stripe=16rows x 64B]: byte = kcol*8192 + (row>>4)*1024 +
//    slot*256 + (row&15)*16. Staging lane l writes byte l*16 -> LINEAR
//    global_load_lds dest + row-major coalesced source; fragment reads are
//    256-B contiguous runs (T2).
//  * 2-barrier phases with setprio(1) around the 8-MFMA cluster (T5; only pays
//    on phase-split schedules per m218b).
// Reads trimmed to 24/tile/wave (a-half0 & b-half1 frags stay live; p3 has no
// ds_read): LDS pipe 2048 cyc/CU/tile < MFMA 2342 -> matrix pipe is the pole.
template <int OUT_F32>
__global__ __launch_bounds__(512, 2) void gemm8r_k(
    const char* __restrict__ A, const char* __restrict__ Bw,
    const float* __restrict__ rs, const float* __restrict__ wscale_p,
    const float* __restrict__ bias, void* __restrict__ outp,
    int M, int N, int K) {
    __shared__ char L[131072];  // A: 2buf x 2half x 16KB at 0; B: same at 65536
    int t = threadIdx.x;
    int lane = t & 63, wv = t >> 6;
    int l31 = lane & 31, kh = lane >> 5;
    int wmi = wv >> 2, wni = wv & 3;

    // XCD-chunked swizzle (grid sizes are multiples of 8)
    int gx = gridDim.x;
    int nwg = gx * gridDim.y;
    int bid = blockIdx.y * gx + blockIdx.x;
    int swz = (bid & 7) * (nwg >> 3) + (bid >> 3);
    int bx = swz % gx, by = swz / gx;
    int m0 = by * 256, n0 = bx * 256;

    // staging: wave w covers stripe w (rows w*16 + (lane&15)), slot lane>>4;
    // per stage call: both k-cols of one half (2 loads/thread = 1 KB/wave each).
    int sl = lane & 15;
    const char* srcA = A  + (long)(m0 + wv * 16 + sl) * K + ((lane >> 4) * 16);
    const char* srcB = Bw + (long)(n0 + wv * 16 + sl) * K + ((lane >> 4) * 16);
    char* dA = L + wv * 1024 + lane * 16;          // lane*16 == slot*256+(row&15)*16
    char* dB = L + 65536 + wv * 1024 + lane * 16;

    auto stA = [&](int Tt, int ih) {
        const char* g = srcA + (long)ih * 128 * K + ((long)Tt << 7);
        char* d = dA + (Tt & 1) * 32768 + ih * 16384;
        async_copy16(g, d);            // k-col 0
        async_copy16(g + 64, d + 8192);// k-col 1
    };
    auto stB = [&](int Tt, int jh) {
        const char* g = srcB + (long)jh * 128 * K + ((long)Tt << 7);
        char* d = dB + (Tt & 1) * 32768 + jh * 16384;
        async_copy16(g, d);
        async_copy16(g + 64, d + 8192);
    };

    // fragment offsets: 16-B k-slot t = 2*ks + kh -> kcol t>>2, in-col slot t&3;
    // row r -> (r>>4)*1024 + (r&15)*16
    int tOff[4];
#pragma unroll
    for (int ks = 0; ks < 4; ks++) {
        int tt = 2 * ks + kh;
        tOff[ks] = (tt >> 2) * 8192 + (tt & 3) * 256;
    }
    int rA[2], rB;
#pragma unroll
    for (int il = 0; il < 2; il++) {
        int r = il * 64 + wmi * 32 + l31;
        rA[il] = (r >> 4) * 1024 + (r & 15) * 16;
    }
    { int r = wni * 32 + l31; rB = (r >> 4) * 1024 + (r & 15) * 16; }

    v16i acc[4][2] = {};  // acc[i][j]: rows m0+i*64+wmi*32, cols n0+j*128+wni*32
    int nK = K >> 7;

    // prologue: T0 complete (8 loads) + T1.{B0,A1} (4 loads); counted wait
    stA(0, 0); stA(0, 1); stB(0, 0); stB(0, 1);
    stB(1, 0); stA(1, 1);
    asm volatile("s_waitcnt vmcnt(4)" ::: "memory");
    asm volatile("s_barrier" ::: "memory");

    for (int T = 0; T < nK; ++T) {
        int bo = (T & 1) * 32768;
        bool pre1 = (T + 1 < nK), pre2 = (T + 2 < nK);
        const char* pA0 = L + bo;
        const char* pA1 = L + bo + 16384;
        const char* pB0 = L + 65536 + bo;
        const char* pB1 = L + 65536 + bo + 16384;
        v4i a0[2][4], a1[2][4], b0[4], b1[4];
        // ---- p0 (ih0,jh0): read A-half0 + B-half0; stage T+1.A0 (other buf) ----
#pragma unroll
        for (int ks = 0; ks < 4; ks++) {
            a0[0][ks] = *(const v4i*)(pA0 + tOff[ks] + rA[0]);
            a0[1][ks] = *(const v4i*)(pA0 + tOff[ks] + rA[1]);
            b0[ks]    = *(const v4i*)(pB0 + tOff[ks] + rB);
        }
        if (pre1) stA(T + 1, 0);
        asm volatile("s_barrier" ::: "memory");
        __builtin_amdgcn_s_setprio(1);
#pragma unroll
        for (int ks = 0; ks < 4; ks++) {
            acc[0][0] = __builtin_amdgcn_mfma_i32_32x32x32_i8(a0[0][ks], b0[ks], acc[0][0], 0, 0, 0);
            acc[1][0] = __builtin_amdgcn_mfma_i32_32x32x32_i8(a0[1][ks], b0[ks], acc[1][0], 0, 0, 0);
        }
        __builtin_amdgcn_s_setprio(0);
        asm volatile("s_barrier" ::: "memory");
        // ---- p1 (ih1,jh0): read A-half1 (b0 reused); stage T+1.B1 (other buf) ----
#pragma unroll
        for (int ks = 0; ks < 4; ks++) {
            a1[0][ks] = *(const v4i*)(pA1 + tOff[ks] + rA[0]);
            a1[1][ks] = *(const v4i*)(pA1 + tOff[ks] + rA[1]);
        }
        if (pre1) stB(T + 1, 1);
        asm volatile("s_barrier" ::: "memory");
        __builtin_amdgcn_s_setprio(1);
#pragma unroll
        for (int ks = 0; ks < 4; ks++) {
            acc[2][0] = __builtin_amdgcn_mfma_i32_32x32x32_i8(a1[0][ks], b0[ks], acc[2][0], 0, 0, 0);
            acc[3][0] = __builtin_amdgcn_mfma_i32_32x32x32_i8(a1[1][ks], b0[ks], acc[3][0], 0, 0, 0);
        }
        __builtin_amdgcn_s_setprio(0);
        asm volatile("s_barrier" ::: "memory");
        // ---- p2 (ih1,jh1): read B-half1 (a1 reused); stage T+2.B0 (cur buf;
        //      B0 last ds_read at p0, returned before p0's MFMA lgkm -> safe) ----
#pragma unroll
        for (int ks = 0; ks < 4; ks++)
            b1[ks] = *(const v4i*)(pB1 + tOff[ks] + rB);
        if (pre2) stB(T + 2, 0);
        asm volatile("s_barrier" ::: "memory");
        __builtin_amdgcn_s_setprio(1);
#pragma unroll
        for (int ks = 0; ks < 4; ks++) {
            acc[2][1] = __builtin_amdgcn_mfma_i32_32x32x32_i8(a1[0][ks], b1[ks], acc[2][1], 0, 0, 0);
            acc[3][1] = __builtin_amdgcn_mfma_i32_32x32x32_i8(a1[1][ks], b1[ks], acc[3][1], 0, 0, 0);
        }
        __builtin_amdgcn_s_setprio(0);
        asm volatile("s_barrier" ::: "memory");
        // ---- p3 (ih0,jh1): no reads (a0,b1 live); stage T+2.A1 (cur buf;
        //      A1 last ds_read at p1 -> safe) ----
        if (pre2) stA(T + 2, 1);
        asm volatile("s_barrier" ::: "memory");
        __builtin_amdgcn_s_setprio(1);
#pragma unroll
        for (int ks = 0; ks < 4; ks++) {
            acc[0][1] = __builtin_amdgcn_mfma_i32_32x32x32_i8(a0[0][ks], b1[ks], acc[0][1], 0, 0, 0);
            acc[1][1] = __builtin_amdgcn_mfma_i32_32x32x32_i8(a0[1][ks], b1[ks], acc[1][1], 0, 0, 0);
        }
        __builtin_amdgcn_s_setprio(0);
        // boundary: T+1 fully landed; T+2.{B0,A1} (4 loads) stay in flight
        if (pre2) asm volatile("s_waitcnt vmcnt(4)" ::: "memory");
        else      asm volatile("s_waitcnt vmcnt(0)" ::: "memory");
        asm volatile("s_barrier" ::: "memory");
    }

    // Epilogue. 32x32 C/D layout: col = lane&31, row = (reg&3) + 8*(reg>>2) + 4*(lane>>5)
    float wsc = *wscale_p;
    float bv[2];
#pragma unroll
    for (int j = 0; j < 2; j++) bv[j] = bias[n0 + j * 128 + wni * 32 + l31];
#pragma unroll
    for (int i = 0; i < 4; i++) {
        int mbase = m0 + i * 64 + wmi * 32 + 4 * kh;
        float fsv[16];
#pragma unroll
        for (int rg = 0; rg < 16; rg++)
            fsv[rg] = rs[mbase + (rg & 3) + 8 * (rg >> 2)] * wsc;
#pragma unroll
        for (int j = 0; j < 2; j++) {
            int ng = n0 + j * 128 + wni * 32 + l31;
#pragma unroll
            for (int rg = 0; rg < 16; rg++) {
                int mg = mbase + (rg & 3) + 8 * (rg >> 2);
                float v = (float)acc[i][j][rg] * fsv[rg] + bv[j];
                long idx = (long)mg * N + ng;
                if (OUT_F32) ((float*)outp)[idx] = v;
                else ((unsigned short*)outp)[idx] = f2bf(v);
            }
        }
    }
}

extern "C" void kernel_launch(void* const* d_in, const int* in_sizes, int n_in,
                              void* d_out, int out_size, void* d_ws, size_t ws_size,
                              hipStream_t stream) {
    const float* x  = (const float*)d_in[0];
    const float* w1 = (const float*)d_in[1];
    const float* b1 = (const float*)d_in[2];
    const float* w2 = (const float*)d_in[3];
    const float* b2 = (const float*)d_in[4];
    float* out = (float*)d_out;

    char* ws = (char*)d_ws;
    float* acc1 = (float*)(ws + 0);
    float* acc2 = (float*)(ws + 4);
    float* wsc1 = (float*)(ws + 8);
    float* wsc2 = (float*)(ws + 12);
    size_t off = 256;
    char* w1q = ws + off; off += (size_t)INNER * DIM;        // 4 MB
    char* w2q = ws + off; off += (size_t)INNER * DIM;        // 4 MB
    char* xq1 = ws + off; off += (size_t)TOK * DIM;          // 16 MB
    float* rs1 = (float*)(ws + off); off += (size_t)TOK * 4; // 64 KB
    char* xq2 = ws + off; off += (size_t)TOK * INNER;        // 64 MB
    float* rs2 = (float*)(ws + off); off += (size_t)TOK * 4; // 64 KB
    unsigned short* h = (unsigned short*)(ws + off);         // 128 MB bf16 (pre-GELU)

    hipMemsetAsync(d_ws, 0, 16, stream);

    int nw = INNER * DIM;
    absmean_k<<<1024, 256, 0, stream>>>(w1, nw / 4, acc1);
    absmean_k<<<1024, 256, 0, stream>>>(w2, nw / 4, acc2);
    wquant_k<<<2048, 256, 0, stream>>>(w1, nw, acc1, wsc1, w1q);
    wquant_k<<<2048, 256, 0, stream>>>(w2, nw, acc2, wsc2, w2q);

    actquant_f32_k<DIM, 4><<<TOK, 256, 0, stream>>>(x, xq1, rs1);
    gemm8r_k<0><<<dim3(INNER / 256, TOK / 256), 512, 0, stream>>>(
        xq1, w1q, rs1, wsc1, b1, (void*)h, TOK, INNER, DIM);
    actquant_bf16_k<INNER, 16><<<TOK, 256, 0, stream>>>(h, xq2, rs2);
    gemm8r_k<1><<<dim3(DIM / 256, TOK / 256), 512, 0, stream>>>(
        xq2, w2q, rs2, wsc2, b2, (void*)out, TOK, DIM, INNER);
}